// Round 15
// baseline (81.230 us; speedup 1.0000x reference)
//
#include <hip/hip_runtime.h>

typedef float __attribute__((ext_vector_type(4))) f32x4;
typedef unsigned int u32;
typedef u32 __attribute__((ext_vector_type(2))) u32x2;

// OUT[n, c=j*8+k, h, w] = sum_{a,m,b} W[j,a,m,b,k] * T[n,(j+a-1)*4+m, (h-1)%28, (w+b-2)...]
//   T[n,cc,h,w] = x[n,cc,h,w] + x[n,cc+128,h,w]
//   gather taps per out w: b=0 <- w-2 (skip w==0), b=1 <- (w-1)%28, b=2 <- w (skip w==27)
//
// R15: tail-free store-coalesced compute. R11==R14==50.3us showed the wall is the
//   output-transpose tail + barrier phase structure (blocks live ~18us, ~2us compute).
//   Thread = (out ch-pair po, row s_, w-quad q), lanes (q,s_) fastest -> stores are
//   natively 224B-contiguous runs (proven: WRITE==100.35MB). NO output LDS round-trip,
//   ONE barrier per block.
// LDS: transposed [2 rows][28 w'][22 pitch] m-pair-packed bf16 dwords = 4.9 KB.
//   Compute reads 3x ds_read_b64 per w-row (g = j-1..j+1 -> 6 adjacent dwords).
// Block: 448 thr (7 waves) = 32 out-pairs x 2 rows x 7 quads; channel-quarter window
//   j in [J0,J0+8), staged groups J0-1..J0+8 (halo zero-filled when OOB -> 0*W safe).
//   grid = 128 x 14 x 4 = 7168; 4 blocks/CU = 28 waves (87%).
// T1 XCD swizzle (7168%8==0): same-n blocks (800KB slab + 25% halo) share one L2.
// Verified pieces: bf16-pair m-packing + v_dot2_f32_bf16 (absmax 0.5 since R7),
//   224B-run staging loads (R10+), 224B-run stores (R11/R14).

#define PITCH 22

__device__ __forceinline__ u32 pack2bf(float lo, float hi) {
    u32 a = __float_as_uint(lo), b = __float_as_uint(hi);
    a = (a + 0x7FFFu + ((a >> 16) & 1u)) >> 16;   // RNE round to bf16
    b = (b + 0x7FFFu + ((b >> 16) & 1u)) >> 16;
    return a | (b << 16);
}

__device__ __forceinline__ float dot2bf(u32 t2, u32 w2, float acc) {
    asm("v_dot2_f32_bf16 %0, %1, %2, %0" : "+v"(acc) : "v"(t2), "v"(w2));
    return acc;
}

__global__ __launch_bounds__(448, 7) void fused_shift_conv(
    const float* __restrict__ x, const float* __restrict__ Wt, float* __restrict__ out)
{
    __shared__ __align__(8) u32 L[56 * PITCH];   // 4.9 KB

    const int bid  = blockIdx.x;
    const int l    = (bid & 7) * 896 + (bid >> 3);   // XCD-bijective swizzle
    const int qblk = l & 3;                          // channel quarter
    const int rest = l >> 2;
    const int n    = rest / 14;
    const int b2   = rest - n * 14;
    const int h0   = b2 * 2;                         // output rows h0, h0+1
    const int J0   = qblk * 8;

    const int tid = threadIdx.x;
    const float* xn = x + (size_t)n * 200704;

    // ---- staging: 20 local pairs x 2 rows x 7 quads = 280 items (224B-run loads) ----
    if (tid < 280) {
        const int pl  = tid / 14;       // local pair 0..19 = (gl<<1)|mp
        const int rem = tid - pl * 14;
        const int row = rem / 7;        // input row 0..1
        const int q   = rem - row * 7;  // quad 0..6
        const int gl  = pl >> 1;        // local group 0..9
        const int mp  = pl & 1;         // m-pair
        const int g   = J0 - 1 + gl;    // global group -1..32
        int hs = h0 - 1 + row; if (hs < 0) hs = 27;
        u32 wv0 = 0, wv1 = 0, wv2 = 0, wv3 = 0;     // OOB groups stay zero (0*W safe)
        if (g >= 0 && g <= 31) {
            const float* b0 = xn + (g * 4 + mp * 2) * 784 + hs * 28 + q * 4;
            const f32x4 lo0 = *(const f32x4*)b0;
            const f32x4 lo1 = *(const f32x4*)(b0 + 784);
            const f32x4 hi0 = *(const f32x4*)(b0 + 100352);
            const f32x4 hi1 = *(const f32x4*)(b0 + 100352 + 784);
            const f32x4 s0 = lo0 + hi0, s1 = lo1 + hi1;
            wv0 = pack2bf(s0[0], s1[0]);
            wv1 = pack2bf(s0[1], s1[1]);
            wv2 = pack2bf(s0[2], s1[2]);
            wv3 = pack2bf(s0[3], s1[3]);
        }
        // transposed write: dword (row*28 + w')[pl], w' = q*4+e
        const int rb = (row * 28 + q * 4) * PITCH + pl;
        L[rb            ] = wv0;
        L[rb + PITCH    ] = wv1;
        L[rb + 2 * PITCH] = wv2;
        L[rb + 3 * PITCH] = wv3;
    }

    // ---- thread mapping: tid = po*14 + s_*7 + q ----
    const int po  = tid / 14;           // output channel pair 0..31
    const int r14 = tid - po * 14;
    const int s_  = r14 / 7;            // output row h0 + s_
    const int q   = r14 - s_ * 7;       // w quad 0..6
    const int jl  = po >> 2;            // local group 0..7
    const int kp  = po & 3;             // k-pair

    // ---- weights: w2[ch2][a][mp][b] bf16-pair packed along m ----
    u32 w2[2][3][2][3];
    {
        const float* wpb = Wt + (J0 + jl) * 288 + kp * 2;   // strides 288/96/24/8/1
        #pragma unroll
        for (int c = 0; c < 2; ++c)
            #pragma unroll
            for (int a = 0; a < 3; ++a)
                #pragma unroll
                for (int mp = 0; mp < 2; ++mp)
                    #pragma unroll
                    for (int b = 0; b < 3; ++b)
                        w2[c][a][mp][b] = pack2bf(wpb[a*96 + (2*mp  )*24 + b*8 + c],
                                                  wpb[a*96 + (2*mp+1)*24 + b*8 + c]);
    }

    __syncthreads();                    // the only barrier

    // ---- compute: per w-row 3 ds_read_b64 + up to 36 dot2 (scatter over 3 taps) ----
    float acc[2][4];
    #pragma unroll
    for (int c = 0; c < 2; ++c)
        #pragma unroll
        for (int e = 0; e < 4; ++e) acc[c][e] = 0.f;

    const int colb = (s_ * 28) * PITCH + 2 * jl;
    #pragma unroll
    for (int i = 0; i < 6; ++i) {
        int wr = q * 4 - 2 + i;                       // w' = 4q-2+i mod 28
        wr = (wr < 0) ? wr + 28 : (wr >= 28 ? wr - 28 : wr);
        const u32* rp = &L[colb + wr * PITCH];
        const u32x2 t01 = *(const u32x2*)rp;          // a=0: mp0, mp1
        const u32x2 t23 = *(const u32x2*)(rp + 2);    // a=1
        const u32x2 t45 = *(const u32x2*)(rp + 4);    // a=2
        const u32 Td[6] = {t01[0], t01[1], t23[0], t23[1], t45[0], t45[1]};

        // b=0 tap: out = w'+2 -> e = i  (skip: out w==0 i.e. i==0 && q==0)
        if (i < 4) {
            if (!(i == 0 && q == 0)) {
                #pragma unroll
                for (int c = 0; c < 2; ++c)
                    #pragma unroll
                    for (int a = 0; a < 3; ++a)
                        #pragma unroll
                        for (int mp = 0; mp < 2; ++mp)
                            acc[c][i] = dot2bf(Td[a*2+mp], w2[c][a][mp][0], acc[c][i]);
            }
        }
        // b=1 tap: out = (w'+1)%28 -> e = i-1 (always)
        if (i >= 1 && i <= 4) {
            #pragma unroll
            for (int c = 0; c < 2; ++c)
                #pragma unroll
                for (int a = 0; a < 3; ++a)
                    #pragma unroll
                    for (int mp = 0; mp < 2; ++mp)
                        acc[c][i-1] = dot2bf(Td[a*2+mp], w2[c][a][mp][1], acc[c][i-1]);
        }
        // b=2 tap: out = w' -> e = i-2  (skip: out w==27 i.e. i==5 && q==6)
        if (i >= 2) {
            if (!(i == 5 && q == 6)) {
                #pragma unroll
                for (int c = 0; c < 2; ++c)
                    #pragma unroll
                    for (int a = 0; a < 3; ++a)
                        #pragma unroll
                        for (int mp = 0; mp < 2; ++mp)
                            acc[c][i-2] = dot2bf(Td[a*2+mp], w2[c][a][mp][2], acc[c][i-2]);
            }
        }
    }

    // ---- stores: lanes (q, s_) fastest -> 224 B contiguous per channel ----
    const int c0 = (J0 + jl) * 8 + kp * 2;
    float* op = out + (size_t)n * 200704 + (size_t)c0 * 784 + (h0 + s_) * 28 + q * 4;
    f32x4 o0, o1;
    o0.x = acc[0][0]; o0.y = acc[0][1]; o0.z = acc[0][2]; o0.w = acc[0][3];
    o1.x = acc[1][0]; o1.y = acc[1][1]; o1.z = acc[1][2]; o1.w = acc[1][3];
    *(f32x4*)op = o0;
    *(f32x4*)(op + 784) = o1;
}

extern "C" void kernel_launch(void* const* d_in, const int* in_sizes, int n_in,
                              void* d_out, int out_size, void* d_ws, size_t ws_size,
                              hipStream_t stream) {
    const float* x  = (const float*)d_in[0];   // (128,256,28,28) f32
    const float* Wt = (const float*)d_in[1];   // (32,3,4,3,8)   f32
    float* out      = (float*)d_out;           // (128,256,28,28) f32

    const int nbatch = in_sizes[0] / 200704;   // 128
    // grid = n x 14 h-pairs x 4 channel-quarters = 7168 (multiple of 8 for the swizzle)
    fused_shift_conv<<<nbatch * 56, 448, 0, stream>>>(x, Wt, out);
}